// Round 4
// baseline (473.955 us; speedup 1.0000x reference)
//
#include <hip/hip_runtime.h>

#define NTAGS 48
#define NB    512
#define SLEN  2048

typedef short  short8 __attribute__((ext_vector_type(8)));
typedef float  f32x4  __attribute__((ext_vector_type(4)));
typedef unsigned u32x4 __attribute__((ext_vector_type(4)));
typedef unsigned u32x2 __attribute__((ext_vector_type(2)));

// ---------- cross-lane helpers (wave64, DPP) ----------

__device__ __forceinline__ float rl_f(float v, int l) {
  return __builtin_bit_cast(float, __builtin_amdgcn_readlane(__builtin_bit_cast(int, v), l));
}

template <int CTRL, bool BC>
__device__ __forceinline__ float dpp_mv(float oldv, float v) {
  return __builtin_bit_cast(float, __builtin_amdgcn_update_dpp(
      __builtin_bit_cast(int, oldv), __builtin_bit_cast(int, v), CTRL, 0xF, 0xF, BC));
}

__device__ __forceinline__ float wred_max(float v) {
  v = fmaxf(v, dpp_mv<0x128, false>(v, v));
  v = fmaxf(v, dpp_mv<0x124, false>(v, v));
  v = fmaxf(v, dpp_mv<0x122, false>(v, v));
  v = fmaxf(v, dpp_mv<0x121, false>(v, v));
  v = fmaxf(v, dpp_mv<0x142, false>(v, v));
  v = fmaxf(v, dpp_mv<0x143, false>(v, v));
  return rl_f(v, 63);
}

__device__ __forceinline__ float wred_sum(float v) {
  v += dpp_mv<0x128, true>(0.0f, v);
  v += dpp_mv<0x124, true>(0.0f, v);
  v += dpp_mv<0x122, true>(0.0f, v);
  v += dpp_mv<0x121, true>(0.0f, v);
  v += dpp_mv<0x142, true>(0.0f, v);
  v += dpp_mv<0x143, true>(0.0f, v);
  return rl_f(v, 63);
}

// quad_mix(a,b) -> Z rows = [a@q0, a@q2, b@q0, b@q2], W rows = [a@q1, a@q3, b@q1, b@q3]
// (rows = 16-lane groups; per-column, i.e. lane&15 preserved)
__device__ __forceinline__ void quad_mix(unsigned a, unsigned b, unsigned& Z, unsigned& W) {
#if __has_builtin(__builtin_amdgcn_permlane32_swap) && __has_builtin(__builtin_amdgcn_permlane16_swap)
  u32x2 uv = __builtin_amdgcn_permlane32_swap(a, b, false, false);
  u32x2 zw = __builtin_amdgcn_permlane16_swap(uv[0], uv[1], false, false);
  Z = zw[0]; W = zw[1];
#else
  const int lane = threadIdx.x & 63;
  const int c = lane & 15;
  const int hi = (lane >> 4) & 1;          // odd quads read from +32
  const int s1 = (c + hi * 32) << 2;
  const int s2 = (c + 16 + hi * 32) << 2;
  unsigned za = __builtin_amdgcn_ds_bpermute(s1, a);
  unsigned zb = __builtin_amdgcn_ds_bpermute(s1, b);
  unsigned wa_ = __builtin_amdgcn_ds_bpermute(s2, a);
  unsigned wb_ = __builtin_amdgcn_ds_bpermute(s2, b);
  Z = (lane < 32) ? za : zb;
  W = (lane < 32) ? wa_ : wb_;
#endif
}

// bf16 packs: low half of dword = first arg
__device__ __forceinline__ unsigned bpack_tr(float x, float y) {  // truncate (fast, per-step)
  return __builtin_amdgcn_perm(__builtin_bit_cast(unsigned, y),
                               __builtin_bit_cast(unsigned, x), 0x07060302u);
}
__device__ __forceinline__ unsigned bpack_rne(float x, float y) { // round-nearest (setup)
  unsigned ux = __builtin_bit_cast(unsigned, x);
  unsigned uy = __builtin_bit_cast(unsigned, y);
  ux += 0x7FFFu + ((ux >> 16) & 1u);
  uy += 0x7FFFu + ((uy >> 16) & 1u);
  return (ux >> 16) | (uy & 0xFFFF0000u);
}

// P12 (C-layout: tile t, reg r -> tag 16t+4q+r) -> B fragments (k = 8q+j per lane)
__device__ __forceinline__ void p_to_b(const float* P, u32x4& B0, u32x4& B1) {
  unsigned d00 = bpack_tr(P[0], P[1]);
  unsigned d01 = bpack_tr(P[2], P[3]);
  unsigned d10 = bpack_tr(P[4], P[5]);
  unsigned d11 = bpack_tr(P[6], P[7]);
  unsigned d20 = bpack_tr(P[8], P[9]);
  unsigned d21 = bpack_tr(P[10], P[11]);
  unsigned b0, b1, b2, b3, b4, b5, b6, b7;
  quad_mix(d00, d10, b0, b2);
  quad_mix(d01, d11, b1, b3);
  quad_mix(d20, d20, b4, b6);   // rows 2,3 garbage -> killed by zero rows of A chunk1
  quad_mix(d21, d21, b5, b7);
  B0[0] = b0; B0[1] = b1; B0[2] = b2; B0[3] = b3;
  B1[0] = b4; B1[1] = b5; B1[2] = b6; B1[3] = b7;
}

// per-chain max across the 4 quads (value already max'd in-lane)
__device__ __forceinline__ float quad_max(float m) {
  unsigned z, w;
  quad_mix(__builtin_bit_cast(unsigned, m), __builtin_bit_cast(unsigned, m), z, w);
  m = fmaxf(__builtin_bit_cast(float, z), __builtin_bit_cast(float, w));
  quad_mix(__builtin_bit_cast(unsigned, m), __builtin_bit_cast(unsigned, m), z, w);
  return fmaxf(__builtin_bit_cast(float, z), __builtin_bit_cast(float, w));
}

// exact pow2 renorm of 12 values; cl += e*ln2
__device__ __forceinline__ void renorm12(float* P, float& cl) {
  float m = P[0];
#pragma unroll
  for (int i = 1; i < 12; ++i) m = fmaxf(m, P[i]);
  m = quad_max(m);
  int e = ((__builtin_bit_cast(int, m) >> 23) & 255) - 127;
  float r = __builtin_bit_cast(float, (127 - e) << 23);
#pragma unroll
  for (int i = 0; i < 12; ++i) P[i] *= r;
  cl += (float)e * 0.6931471805599453f;
}

__device__ __forceinline__ f32x4 mfma16(short8 a, short8 b, f32x4 c) {
  return __builtin_amdgcn_mfma_f32_16x16x32_bf16(a, b, c, 0, 0, 0);
}

// ---------- fused kernel ----------
// blocks [0,32): forward scan, 16 batches/wave -> alpha_1024
// blocks [32,64): backward scan, 16 batches/wave -> beta_1024
// blocks [64,576): gold-path score + mask count, one wave per batch

extern "C" __global__ __launch_bounds__(64, 1)
void crf_main(const float* __restrict__ emis,
              const float* __restrict__ trans,
              const float* __restrict__ startt,
              const float* __restrict__ endt,
              const int*   __restrict__ tags,
              const float* __restrict__ mask,
              float* __restrict__ wa, float* __restrict__ wb,
              float* __restrict__ wsc, int* __restrict__ wcnt) {
  __shared__ float st[NTAGS * NTAGS];
  const int lane = threadIdx.x;
  const int bid  = blockIdx.x;

  if (bid >= 64) {
    // ----- score path (R3-verified) -----
    const int b = bid - 64;
    for (int k = lane; k < NTAGS * NTAGS; k += 64) st[k] = trans[k];
    __syncthreads();
    const int* tb = tags + (size_t)b * SLEN;
    float ssum = 0.0f, csum = 0.0f;
    for (int it = 0; it < SLEN / 64; ++it) {
      const int t = it * 64 + lane;
      int   cur = tb[t];
      float mv  = mask[(size_t)b * SLEN + t];
      float ev  = emis[((size_t)b * SLEN + t) * NTAGS + cur];
      float s;
      if (t == 0) {
        s = startt[cur] + ev;  // unmasked per reference
      } else {
        int prev = tb[t - 1];
        s = (mv != 0.0f) ? (st[prev * NTAGS + cur] + ev) : 0.0f;
      }
      ssum += s;
      csum += (mv != 0.0f) ? 1.0f : 0.0f;
    }
    ssum = wred_sum(ssum);
    csum = wred_sum(csum);
    if (lane == 0) { wsc[b] = ssum; wcnt[b] = (int)(csum + 0.5f); }
    return;
  }

  // ----- MFMA scan path -----
  const bool fwd = bid < 32;
  const int  b0  = (fwd ? bid : bid - 32) * 16;
  const int  l   = lane & 15;      // chain (batch b0+l); also m/n index of MFMA
  const int  q   = lane >> 4;      // quad
  const int  b   = b0 + l;

  const float* eb = emis + (size_t)b * SLEN * NTAGS;
  const float* mb = mask + (size_t)b * SLEN;

  // A fragments: E_op in bf16. A[m=l][k=8q+j], tiles tt (m-block 16tt), chunks h (k-block 32h).
  // fwd: A = E^T  -> A[m][k] = exp(trans[(32h+k)][16tt+m]); zero when 32h+k >= 48
  // bwd: A = E    -> A[m][k] = exp(trans[(16tt+m)][32h+k]); zero when 32h+k >= 48
  short8 Af[3][2];
#pragma unroll
  for (int tt = 0; tt < 3; ++tt) {
#pragma unroll
    for (int h = 0; h < 2; ++h) {
      u32x4 dw;
#pragma unroll
      for (int d = 0; d < 4; ++d) {
        int k0 = 8 * q + 2 * d;
        int i0 = 32 * h + k0;
        float x, y;
        if (fwd) {
          x = (i0 < 48)     ? __expf(trans[i0 * NTAGS + 16 * tt + l])       : 0.0f;
          y = (i0 + 1 < 48) ? __expf(trans[(i0 + 1) * NTAGS + 16 * tt + l]) : 0.0f;
        } else {
          x = (i0 < 48)     ? __expf(trans[(16 * tt + l) * NTAGS + i0])     : 0.0f;
          y = (i0 + 1 < 48) ? __expf(trans[(16 * tt + l) * NTAGS + i0 + 1]) : 0.0f;
        }
        dw[d] = bpack_rne(x, y);
      }
      Af[tt][h] = __builtin_bit_cast(short8, dw);
    }
  }

  f32x4 ring[8][3];   // emission prefetch ring: [t&7][tile], per-lane f32x4 at tag 16*tt+4q
  float mbuf[8];
  float P[12];        // linear-domain state, C-layout
  float ee[12];       // exp(emissions) for the step about to be consumed
  float cl;
  u32x4 B0, B1;       // B fragments (loop-carried)
  const f32x4 zf = {0.f, 0.f, 0.f, 0.f};

  if (fwd) {
    // init: P = exp(start + emit_0 - m0), cl = m0
    float a0[12], ml;
#pragma unroll
    for (int tt = 0; tt < 3; ++tt) {
      f32x4 ev = *(const f32x4*)(eb + 16 * tt + 4 * q);
      f32x4 sv = *(const f32x4*)(startt + 16 * tt + 4 * q);
#pragma unroll
      for (int r = 0; r < 4; ++r) a0[4 * tt + r] = sv[r] + ev[r];
    }
    ml = a0[0];
#pragma unroll
    for (int i = 1; i < 12; ++i) ml = fmaxf(ml, a0[i]);
    ml = quad_max(ml);
#pragma unroll
    for (int i = 0; i < 12; ++i) P[i] = __expf(a0[i] - ml);
    cl = ml;
    p_to_b(P, B0, B1);

#pragma unroll
    for (int k = 1; k <= 8; ++k) {
#pragma unroll
      for (int tt = 0; tt < 3; ++tt)
        ring[k & 7][tt] = *(const f32x4*)(eb + (size_t)k * NTAGS + 16 * tt + 4 * q);
      mbuf[k & 7] = mb[k];
    }
#pragma unroll
    for (int tt = 0; tt < 3; ++tt)
#pragma unroll
      for (int r = 0; r < 4; ++r) ee[4 * tt + r] = __expf(ring[1][tt][r]);

    for (int g = 0; g < 128; ++g) {
#pragma unroll
      for (int u = 0; u < 8; ++u) {
        const int t  = 1 + 8 * g + u;
        const int sl = t & 7, sl1 = (t + 1) & 7;
        // off-chain: next step's exp(emit)
        float een[12];
#pragma unroll
        for (int tt = 0; tt < 3; ++tt)
#pragma unroll
          for (int r = 0; r < 4; ++r) een[4 * tt + r] = __expf(ring[sl1][tt][r]);
        // chain: 6 MFMA -> acc, * ee, mask-select
        f32x4 a0v = mfma16(Af[0][0], __builtin_bit_cast(short8, B0), zf);
        f32x4 a1v = mfma16(Af[1][0], __builtin_bit_cast(short8, B0), zf);
        f32x4 a2v = mfma16(Af[2][0], __builtin_bit_cast(short8, B0), zf);
        a0v = mfma16(Af[0][1], __builtin_bit_cast(short8, B1), a0v);
        a1v = mfma16(Af[1][1], __builtin_bit_cast(short8, B1), a1v);
        a2v = mfma16(Af[2][1], __builtin_bit_cast(short8, B1), a2v);
        float mv = mbuf[sl];
        bool live = (mv != 0.0f);
        float nP[12];
#pragma unroll
        for (int r = 0; r < 4; ++r) {
          nP[r]     = a0v[r] * ee[r];
          nP[4 + r] = a1v[r] * ee[4 + r];
          nP[8 + r] = a2v[r] * ee[8 + r];
        }
        if (__all(live)) {
#pragma unroll
          for (int i = 0; i < 12; ++i) P[i] = nP[i];
        } else {
#pragma unroll
          for (int i = 0; i < 12; ++i) P[i] = live ? nP[i] : P[i];
        }
        // prefetch t+8 into freed slot
#pragma unroll
        for (int tt = 0; tt < 3; ++tt)
          ring[sl][tt] = *(const f32x4*)(eb + (size_t)(t + 8) * NTAGS + 16 * tt + 4 * q);
        mbuf[sl] = mb[t + 8];
        if (u == 7) renorm12(P, cl);
        p_to_b(P, B0, B1);
#pragma unroll
        for (int i = 0; i < 12; ++i) ee[i] = een[i];
      }
    }
#pragma unroll
    for (int tt = 0; tt < 3; ++tt) {
      f32x4 o;
#pragma unroll
      for (int r = 0; r < 4; ++r) o[r] = __logf(P[4 * tt + r]) + cl;
      *(f32x4*)(wa + (size_t)b * NTAGS + 16 * tt + 4 * q) = o;
    }
  } else {
    // init: beta_2047 = exp(end - m0)
    float a0[12], ml;
#pragma unroll
    for (int tt = 0; tt < 3; ++tt) {
      f32x4 sv = *(const f32x4*)(endt + 16 * tt + 4 * q);
#pragma unroll
      for (int r = 0; r < 4; ++r) a0[4 * tt + r] = sv[r];
    }
    ml = a0[0];
#pragma unroll
    for (int i = 1; i < 12; ++i) ml = fmaxf(ml, a0[i]);
    ml = quad_max(ml);
#pragma unroll
    for (int i = 0; i < 12; ++i) P[i] = __expf(a0[i] - ml);
    cl = ml;

#pragma unroll
    for (int k = 0; k < 8; ++k) {
      const int t = 2047 - k;
#pragma unroll
      for (int tt = 0; tt < 3; ++tt)
        ring[t & 7][tt] = *(const f32x4*)(eb + (size_t)t * NTAGS + 16 * tt + 4 * q);
      mbuf[t & 7] = mb[t];
    }
#pragma unroll
    for (int tt = 0; tt < 3; ++tt)
#pragma unroll
      for (int r = 0; r < 4; ++r) ee[4 * tt + r] = __expf(ring[7][tt][r]);  // ee[2047]

    // step body: Q = P*ee_t -> B -> mfma -> candidate beta_{t-1}; select by mask_t
#define BWD_STEP(T, DO_RENORM)                                                        \
    {                                                                                 \
      const int t = (T);                                                              \
      const int sl = t & 7, slm = (t - 1) & 7;                                        \
      float een[12];                                                                  \
      _Pragma("unroll")                                                               \
      for (int tt = 0; tt < 3; ++tt)                                                  \
        _Pragma("unroll")                                                             \
        for (int r = 0; r < 4; ++r) een[4 * tt + r] = __expf(ring[slm][tt][r]);       \
      float Q[12];                                                                    \
      _Pragma("unroll")                                                               \
      for (int i = 0; i < 12; ++i) Q[i] = P[i] * ee[i];                               \
      p_to_b(Q, B0, B1);                                                              \
      f32x4 a0v = mfma16(Af[0][0], __builtin_bit_cast(short8, B0), zf);               \
      f32x4 a1v = mfma16(Af[1][0], __builtin_bit_cast(short8, B0), zf);               \
      f32x4 a2v = mfma16(Af[2][0], __builtin_bit_cast(short8, B0), zf);               \
      a0v = mfma16(Af[0][1], __builtin_bit_cast(short8, B1), a0v);                    \
      a1v = mfma16(Af[1][1], __builtin_bit_cast(short8, B1), a1v);                    \
      a2v = mfma16(Af[2][1], __builtin_bit_cast(short8, B1), a2v);                    \
      float mv = mbuf[sl];                                                            \
      bool live = (mv != 0.0f);                                                       \
      float nP[12];                                                                   \
      _Pragma("unroll")                                                               \
      for (int r = 0; r < 4; ++r) {                                                   \
        nP[r] = a0v[r]; nP[4 + r] = a1v[r]; nP[8 + r] = a2v[r];                       \
      }                                                                               \
      if (__all(live)) {                                                              \
        _Pragma("unroll")                                                             \
        for (int i = 0; i < 12; ++i) P[i] = nP[i];                                    \
      } else {                                                                        \
        _Pragma("unroll")                                                             \
        for (int i = 0; i < 12; ++i) P[i] = live ? nP[i] : P[i];                      \
      }                                                                               \
      _Pragma("unroll")                                                               \
      for (int tt = 0; tt < 3; ++tt)                                                  \
        ring[sl][tt] = *(const f32x4*)(eb + (size_t)(t - 8) * NTAGS + 16 * tt + 4 * q); \
      mbuf[sl] = mb[t - 8];                                                           \
      if (DO_RENORM) renorm12(P, cl);                                                 \
      _Pragma("unroll")                                                               \
      for (int i = 0; i < 12; ++i) ee[i] = een[i];                                    \
    }

#pragma unroll
    for (int pt = 0; pt < 7; ++pt) BWD_STEP(2047 - pt, pt == 6)
    for (int g = 0; g < 127; ++g) {
#pragma unroll
      for (int u = 0; u < 8; ++u) BWD_STEP(2040 - 8 * g - u, u == 7)
    }
#undef BWD_STEP

#pragma unroll
    for (int tt = 0; tt < 3; ++tt) {
      f32x4 o;
#pragma unroll
      for (int r = 0; r < 4; ++r) o[r] = __logf(P[4 * tt + r]) + cl;
      *(f32x4*)(wb + (size_t)b * NTAGS + 16 * tt + 4 * q) = o;
    }
  }
}

// ---------- combine: partition_b = lse(alpha_1024 + beta_1024); loss ----------

extern "C" __global__ __launch_bounds__(64)
void crf_combine(const float* __restrict__ wa, const float* __restrict__ wb,
                 const float* __restrict__ wsc, const int* __restrict__ wcnt,
                 const int* __restrict__ tags, const float* __restrict__ endt,
                 float* __restrict__ out) {
  const int b    = blockIdx.x;
  const int lane = threadIdx.x;
  float v = -1e30f;
  if (lane < NTAGS) v = wa[b * NTAGS + lane] + wb[b * NTAGS + lane];
  float m = wred_max(v);
  float s = wred_sum(__expf(v - m));
  float part = m + __logf(s);
  int   last = wcnt[b] - 1;
  float score = wsc[b] + endt[tags[(size_t)b * SLEN + last]];
  if (lane == 0) atomicAdd(out, (part - score) * (1.0f / (float)NB));
}

// ---------- launch ----------

extern "C" void kernel_launch(void* const* d_in, const int* in_sizes, int n_in,
                              void* d_out, int out_size, void* d_ws, size_t ws_size,
                              hipStream_t stream) {
  const float* emis  = (const float*)d_in[0];
  const float* trans = (const float*)d_in[1];
  const float* stt   = (const float*)d_in[2];
  const float* ent   = (const float*)d_in[3];
  const int*   tags  = (const int*)d_in[4];
  const float* mask  = (const float*)d_in[5];

  float* wa   = (float*)d_ws;            // [NB][NTAGS]
  float* wb   = wa + NB * NTAGS;         // [NB][NTAGS]
  float* wsc  = wb + NB * NTAGS;         // [NB]
  int*   wcnt = (int*)(wsc + NB);        // [NB]

  hipMemsetAsync(d_out, 0, sizeof(float), stream);
  crf_main<<<64 + NB, 64, 0, stream>>>(emis, trans, stt, ent, tags, mask,
                                       wa, wb, wsc, wcnt);
  crf_combine<<<NB, 64, 0, stream>>>(wa, wb, wsc, wcnt, tags, ent, (float*)d_out);
}